// Round 4
// baseline (363.714 us; speedup 1.0000x reference)
//
#include <hip/hip_runtime.h>

// ---------------------------------------------------------------------------
// PointTransformerForSegmentation: kNN(k=3) -> angle embed -> posembed ->
// two 1x1-conv GEMMs (bf16 MFMA) -> neighbor-sum -> (B, H1, N1) f32 out.
//
// Shapes: B=8 N1=2048 N2=128 C2=256 K=3 D_POS=32 H0=512 H1=1024
// Round-4 diffs vs round-3 (proven):
//   * GEMMs: B (weights) loaded DIRECT global->VGPR (L2-resident, issued
//     before the staging barrier so its vmcnt drain covers them). Only A is
//     staged in LDS -> halves LDS read traffic (the measured floor).
//   * gemm1 skips j=3 H0 stores (gemm2 discards those acc rows; poisoned
//     bf16 0xAAAA = tiny finite denormal, confined to its own C row).
// ---------------------------------------------------------------------------

typedef unsigned short u16;
typedef __bf16 bf16x8 __attribute__((ext_vector_type(8)));
typedef float f32x4 __attribute__((ext_vector_type(4)));
typedef u16 u16x8 __attribute__((ext_vector_type(8)));

#define BQ 8
#define N1Q 2048
#define N2Q 128
#define C2Q 256
#define DPOS 32
#define H0Q 512
#define H1Q 1024
#define KDIM1 288            // C2 + DPOS
#define NQUERY (BQ * N1Q)    // 16384
#define MROWS (NQUERY * 4)   // 65536 padded rows

// ws layout (bytes) -- identical to rounds 1/3 (proven to fit):
#define WS_W0BF 0u
#define WS_W1BF 294912u                      // 512*288*2
#define WS_X 1343488u                        // +1024*512*2
#define WS_H0 39092224u                      // +65536*288*2
// end: 39092224 + 65536*512*2 = 106201088 bytes (~101 MB)

__device__ __forceinline__ u16 f2bf(float f) {
  unsigned int u = __builtin_bit_cast(unsigned int, f);
  return (u16)((u + 0x7FFFu + ((u >> 16) & 1u)) >> 16);
}

__device__ __forceinline__ void load16_lds(const void* g, void* l) {
  __builtin_amdgcn_global_load_lds(
      (const __attribute__((address_space(1))) unsigned int*)g,
      (__attribute__((address_space(3))) unsigned int*)l, 16, 0, 0);
}

// ---------------------------------------------------------------------------
__global__ void convert_weights(const float* __restrict__ w0,
                                const float* __restrict__ w1,
                                u16* __restrict__ w0b, u16* __restrict__ w1b) {
  int i = blockIdx.x * 256 + threadIdx.x;  // grid covers 671744 exactly
  if (i < 147456) {
    w0b[i] = f2bf(w0[i]);
  } else {
    int j = i - 147456;  // < 524288
    w1b[j] = f2bf(w1[j]);
  }
}

// ---------------------------------------------------------------------------
// build_x: one block = 128 queries (same batch b). Phase1: per-thread kNN +
// rp (threads 0..127). Phase2: cooperative coalesced write of padded X rows
// (bf16), row = query*4 + j, incl. zero row j=3.  (unchanged from round 3)
__global__ void build_x(const float* __restrict__ xyz1,
                        const float* __restrict__ xyz2,
                        const float* __restrict__ feat2,
                        const float* __restrict__ lrf2,
                        const float* __restrict__ w_pos,
                        const float* __restrict__ pscale,
                        const float* __restrict__ pbias,
                        u16* __restrict__ X) {
  __shared__ float xyz2s[N2Q * 3];
  __shared__ float n2s[N2Q];
  __shared__ float lrfs[N2Q * 9];
  __shared__ float wps[DPOS * 4];
  __shared__ float pss[DPOS];
  __shared__ float pbs[DPOS];
  __shared__ int idxb[128 * 3];
  __shared__ float rpb[128 * 3 * 4];

  const int t = threadIdx.x;
  const int qb = blockIdx.x * 128;   // 128 blocks
  const int b = qb >> 11;            // uniform per block (128 | 2048)

  for (int i = t; i < N2Q * 3; i += 256) xyz2s[i] = xyz2[b * N2Q * 3 + i];
  for (int i = t; i < N2Q * 9; i += 256) lrfs[i] = lrf2[b * N2Q * 9 + i];
  if (t < DPOS * 4) wps[t] = w_pos[t];
  if (t < DPOS) { pss[t] = pscale[t]; pbs[t] = pbias[t]; }
  __syncthreads();
  if (t < N2Q) {
    float x = xyz2s[t * 3], y = xyz2s[t * 3 + 1], z = xyz2s[t * 3 + 2];
    n2s[t] = x * x + y * y + z * z;
  }
  __syncthreads();

  if (t < 128) {
    const int q = qb + t;
    const float px = xyz1[q * 3], py = xyz1[q * 3 + 1], pz = xyz1[q * 3 + 2];
    const float pn = px * px + py * py + pz * pz;
    float d0 = 1e30f, d1 = 1e30f, d2v = 1e30f;
    int i0 = 0, i1 = 0, i2 = 0;
    for (int i = 0; i < N2Q; i++) {
      float dt = px * xyz2s[i * 3] + py * xyz2s[i * 3 + 1] + pz * xyz2s[i * 3 + 2];
      float d = pn + n2s[i] - 2.f * dt;
      if (d < d0) {
        d2v = d1; i2 = i1; d1 = d0; i1 = i0; d0 = d; i0 = i;
      } else if (d < d1) {
        d2v = d1; i2 = i1; d1 = d; i1 = i;
      } else if (d < d2v) {
        d2v = d; i2 = i;
      }
    }
    int sel0 = i0, sel1 = i1, sel2 = i2;
    #pragma unroll
    for (int j = 0; j < 3; j++) {
      int id = (j == 0) ? sel0 : (j == 1) ? sel1 : sel2;
      float rx = px - xyz2s[id * 3];
      float ry = py - xyz2s[id * 3 + 1];
      float rz = pz - xyz2s[id * 3 + 2];
      float rn = sqrtf(rx * rx + ry * ry + rz * rz);
      float inv = 1.f / fmaxf(rn, 1e-12f);
      float ux = rx * inv, uy = ry * inv, uz = rz * inv;
      const float* L = lrfs + id * 9;
      float a0 = L[0] * ux + L[1] * uy + L[2] * uz;
      float a1 = L[3] * ux + L[4] * uy + L[5] * uz;
      float a2 = L[6] * ux + L[7] * uy + L[8] * uz;
      idxb[t * 3 + j] = id;
      float* rp = rpb + (t * 3 + j) * 4;
      rp[0] = rn; rp[1] = a0; rp[2] = a1; rp[3] = a2;
    }
  }
  __syncthreads();

  for (int cix = t; cix < 18432; cix += 256) {
    int rl = cix / 36;           // local row 0..511
    int ch = cix - rl * 36;      // chunk 0..35
    int ql = rl >> 2, j = rl & 3;
    u16x8 val;
    if (j == 3) {
      #pragma unroll
      for (int e = 0; e < 8; e++) val[e] = 0;
    } else if (ch < 32) {
      int id = idxb[ql * 3 + j];
      const float* f = feat2 + ((size_t)b * N2Q + id) * C2Q + ch * 8;
      #pragma unroll
      for (int e = 0; e < 8; e++) val[e] = f2bf(f[e]);
    } else {
      const float* rp = rpb + (ql * 3 + j) * 4;
      float r0 = rp[0], r1 = rp[1], r2 = rp[2], r3 = rp[3];
      int ob = (ch - 32) * 8;
      #pragma unroll
      for (int e = 0; e < 8; e++) {
        int o = ob + e;
        float v = wps[o * 4] * r0 + wps[o * 4 + 1] * r1 +
                  wps[o * 4 + 2] * r2 + wps[o * 4 + 3] * r3;
        v = v * pss[o] + pbs[o];
        v = (v >= 0.f) ? v : 0.2f * v;  // LeakyReLU(0.2)
        val[e] = f2bf(v);
      }
    }
    *(u16x8*)(X + ((size_t)(qb * 4) + rl) * KDIM1 + ch * 8) = val;
  }
}

// ---------------------------------------------------------------------------
// GEMM1: H0[m][n] = relu((X[m][:] . W0[n][:]) * s0[n] + b0[n]) as bf16.
// A staged in LDS; W0 fragments loaded DIRECT from global (L2-hot, issued
// pre-barrier). Skips j=3 row stores (discarded downstream).
__global__ void gemm1(const u16* __restrict__ A, const u16* __restrict__ W,
                      const float* __restrict__ s, const float* __restrict__ bz,
                      u16* __restrict__ H) {
  constexpr int K = KDIM1, N = H0Q;
  __shared__ alignas(16) u16 As[128 * 32];
  const int id = blockIdx.x;             // 2048 blocks
  const int xcd = id & 7, g = id >> 3;   // g: 0..255
  const int m0 = ((g >> 2) * 8 + xcd) * 128;  // m-tile 0..511
  const int n0 = (g & 3) * 128;               // n-tile 0..3
  const int t = threadIdx.x;
  const int wv = t >> 6, lane = t & 63;
  const int wm = wv >> 1, wn = wv & 1;
  const int quad = lane >> 4, cc = lane & 15;
  const int srow = wv * 16 + (lane >> 2);  // + i*64 per round
  const int scol = (lane & 3) * 8;
  f32x4 acc[4][4] = {};

  for (int k0 = 0; k0 < K; k0 += 32) {
    // direct B loads (drained by the barrier's vmcnt(0); data ready after)
    bf16x8 bf[4];
    #pragma unroll
    for (int nt = 0; nt < 4; nt++)
      bf[nt] = *(const bf16x8*)(W + (size_t)(n0 + wn * 64 + nt * 16 + cc) * K +
                                k0 + quad * 8);
    #pragma unroll
    for (int i = 0; i < 2; i++)
      load16_lds(A + (size_t)(m0 + srow + i * 64) * K + k0 + scol,
                 (char*)As + i * 4096 + wv * 1024 + (lane << 4));
    __syncthreads();
    bf16x8 af[4];
    #pragma unroll
    for (int mt = 0; mt < 4; mt++)
      af[mt] = *(const bf16x8*)(As + (wm * 64 + mt * 16 + cc) * 32 + quad * 8);
    #pragma unroll
    for (int mt = 0; mt < 4; mt++)
      #pragma unroll
      for (int nt = 0; nt < 4; nt++)
        acc[mt][nt] = __builtin_amdgcn_mfma_f32_16x16x32_bf16(
            af[mt], bf[nt], acc[mt][nt], 0, 0, 0);
    __syncthreads();
  }

  #pragma unroll
  for (int nt = 0; nt < 4; nt++) {
    int gn = n0 + wn * 64 + nt * 16 + cc;
    float sv = s[gn], bv = bz[gn];
    #pragma unroll
    for (int mt = 0; mt < 4; mt++) {
      int gm = m0 + wm * 64 + mt * 16 + quad * 4;
      #pragma unroll
      for (int r = 0; r < 3; r++) {  // r==3 is a j=3 pad row: skip store
        float h = acc[mt][nt][r] * sv + bv;
        h = h > 0.f ? h : 0.f;
        H[(size_t)(gm + r) * N + gn] = f2bf(h);
      }
    }
  }
}

// ---------------------------------------------------------------------------
// GEMM2: h1 = relu((H0 . W1^T) * s1 + b1); in-lane sum over j=0..2 (reg 0..2
// of each quad = 3 real neighbor rows of one query); write out[b][n][n1] f32.
// A staged in LDS; W1 fragments loaded DIRECT from global (L2-hot).
__global__ void gemm2(const u16* __restrict__ A, const u16* __restrict__ W,
                      const float* __restrict__ s, const float* __restrict__ bz,
                      float* __restrict__ out) {
  constexpr int K = H0Q;  // 512
  __shared__ alignas(16) u16 As[128 * 32];
  const int id = blockIdx.x;             // 4096 blocks
  const int xcd = id & 7, g = id >> 3;   // g: 0..511
  const int m0 = ((g >> 3) * 8 + xcd) * 128;  // m-tile 0..511
  const int n0 = (g & 7) * 128;               // n-tile 0..7
  const int t = threadIdx.x;
  const int wv = t >> 6, lane = t & 63;
  const int wm = wv >> 1, wn = wv & 1;
  const int quad = lane >> 4, cc = lane & 15;
  const int srow = wv * 16 + (lane >> 2);
  const int scol = (lane & 3) * 8;
  f32x4 acc[4][4] = {};

  for (int k0 = 0; k0 < K; k0 += 32) {
    bf16x8 bf[4];
    #pragma unroll
    for (int nt = 0; nt < 4; nt++)
      bf[nt] = *(const bf16x8*)(W + (size_t)(n0 + wn * 64 + nt * 16 + cc) * K +
                                k0 + quad * 8);
    #pragma unroll
    for (int i = 0; i < 2; i++)
      load16_lds(A + (size_t)(m0 + srow + i * 64) * K + k0 + scol,
                 (char*)As + i * 4096 + wv * 1024 + (lane << 4));
    __syncthreads();
    bf16x8 af[4];
    #pragma unroll
    for (int mt = 0; mt < 4; mt++)
      af[mt] = *(const bf16x8*)(As + (wm * 64 + mt * 16 + cc) * 32 + quad * 8);
    #pragma unroll
    for (int mt = 0; mt < 4; mt++)
      #pragma unroll
      for (int nt = 0; nt < 4; nt++)
        acc[mt][nt] = __builtin_amdgcn_mfma_f32_16x16x32_bf16(
            af[mt], bf[nt], acc[mt][nt], 0, 0, 0);
    __syncthreads();
  }

  #pragma unroll
  for (int nt = 0; nt < 4; nt++) {
    int gn = n0 + wn * 64 + nt * 16 + cc;  // output channel 0..1023
    float sv = s[gn], bv = bz[gn];
    #pragma unroll
    for (int mt = 0; mt < 4; mt++) {
      int gm = m0 + wm * 64 + mt * 16 + quad * 4;  // multiple of 4
      int query = gm >> 2;
      int bb = query >> 11, n1 = query & 2047;
      f32x4 v = acc[mt][nt];
      float h0v = v[0] * sv + bv; h0v = h0v > 0.f ? h0v : 0.f;
      float h1v = v[1] * sv + bv; h1v = h1v > 0.f ? h1v : 0.f;
      float h2v = v[2] * sv + bv; h2v = h2v > 0.f ? h2v : 0.f;
      out[((size_t)bb * H1Q + gn) * N1Q + n1] = h0v + h1v + h2v;
    }
  }
}

// ---------------------------------------------------------------------------
extern "C" void kernel_launch(void* const* d_in, const int* in_sizes, int n_in,
                              void* d_out, int out_size, void* d_ws,
                              size_t ws_size, hipStream_t stream) {
  const float* xyz1 = (const float*)d_in[0];
  const float* xyz2 = (const float*)d_in[1];
  const float* feat2 = (const float*)d_in[2];
  const float* lrf2 = (const float*)d_in[3];
  const float* w_pos = (const float*)d_in[4];
  const float* pscale = (const float*)d_in[5];
  const float* pbias = (const float*)d_in[6];
  const float* w0 = (const float*)d_in[7];
  const float* s0 = (const float*)d_in[8];
  const float* b0 = (const float*)d_in[9];
  const float* w1 = (const float*)d_in[10];
  const float* s1 = (const float*)d_in[11];
  const float* b1 = (const float*)d_in[12];
  float* out = (float*)d_out;

  char* ws = (char*)d_ws;
  u16* w0bf = (u16*)(ws + WS_W0BF);
  u16* w1bf = (u16*)(ws + WS_W1BF);
  u16* X = (u16*)(ws + WS_X);
  u16* H0 = (u16*)(ws + WS_H0);

  convert_weights<<<671744 / 256, 256, 0, stream>>>(w0, w1, w0bf, w1bf);
  build_x<<<NQUERY / 128, 256, 0, stream>>>(xyz1, xyz2, feat2, lrf2, w_pos,
                                            pscale, pbias, X);
  gemm1<<<dim3((MROWS / 128) * (H0Q / 128)), 256, 0, stream>>>(X, w0bf, s0,
                                                               b0, H0);
  gemm2<<<dim3((MROWS / 128) * (H1Q / 128)), 256, 0, stream>>>(H0, w1bf, s1,
                                                               b1, out);
}

// Round 5
// 268.438 us; speedup vs baseline: 1.3549x; 1.3549x over previous
//
#include <hip/hip_runtime.h>

// ---------------------------------------------------------------------------
// PointTransformerForSegmentation: kNN(k=3) -> angle embed -> posembed ->
// two 1x1-conv GEMMs (bf16 MFMA) -> neighbor-sum -> (B, H1, N1) f32 out.
//
// Shapes: B=8 N1=2048 N2=128 C2=256 K=3 D_POS=32 H0=512 H1=1024
// Round-5: round-3 proven GEMM structure (LDS staging for BOTH operands;
// direct-B of round 4 regressed: 1KB-stride lane gathers) plus:
//   * XOR-swizzled LDS layout (source-column permutation, dst unchanged --
//     global_load_lds needs lane-contiguous dst): chunk (r,c) holds global
//     col c ^ s(r), s(r)=(r+(r>>2))&3 -> fragment reads are 2-way/bank (free).
//   * build_x: 256 blocks x 64 queries (was 128 blocks = half GPU idle).
//   * gemm1 skips j=3 H0 stores (validated round 4).
// ---------------------------------------------------------------------------

typedef unsigned short u16;
typedef __bf16 bf16x8 __attribute__((ext_vector_type(8)));
typedef float f32x4 __attribute__((ext_vector_type(4)));
typedef u16 u16x8 __attribute__((ext_vector_type(8)));

#define BQ 8
#define N1Q 2048
#define N2Q 128
#define C2Q 256
#define DPOS 32
#define H0Q 512
#define H1Q 1024
#define KDIM1 288            // C2 + DPOS
#define NQUERY (BQ * N1Q)    // 16384
#define MROWS (NQUERY * 4)   // 65536 padded rows

// ws layout (bytes) -- identical to rounds 1/3 (proven to fit):
#define WS_W0BF 0u
#define WS_W1BF 294912u                      // 512*288*2
#define WS_X 1343488u                        // +1024*512*2
#define WS_H0 39092224u                      // +65536*288*2
// end: 39092224 + 65536*512*2 = 106201088 bytes (~101 MB)

__device__ __forceinline__ u16 f2bf(float f) {
  unsigned int u = __builtin_bit_cast(unsigned int, f);
  return (u16)((u + 0x7FFFu + ((u >> 16) & 1u)) >> 16);
}

__device__ __forceinline__ void load16_lds(const void* g, void* l) {
  __builtin_amdgcn_global_load_lds(
      (const __attribute__((address_space(1))) unsigned int*)g,
      (__attribute__((address_space(3))) unsigned int*)l, 16, 0, 0);
}

// ---------------------------------------------------------------------------
__global__ void convert_weights(const float* __restrict__ w0,
                                const float* __restrict__ w1,
                                u16* __restrict__ w0b, u16* __restrict__ w1b) {
  int i = blockIdx.x * 256 + threadIdx.x;  // grid covers 671744 exactly
  if (i < 147456) {
    w0b[i] = f2bf(w0[i]);
  } else {
    int j = i - 147456;  // < 524288
    w1b[j] = f2bf(w1[j]);
  }
}

// ---------------------------------------------------------------------------
// build_x: one block = 64 queries (same batch b), 256 blocks. Phase1:
// per-thread kNN + rp (threads 0..63). Phase2: cooperative coalesced write of
// padded X rows (bf16), row = query*4 + j, incl. zero row j=3.
__global__ void build_x(const float* __restrict__ xyz1,
                        const float* __restrict__ xyz2,
                        const float* __restrict__ feat2,
                        const float* __restrict__ lrf2,
                        const float* __restrict__ w_pos,
                        const float* __restrict__ pscale,
                        const float* __restrict__ pbias,
                        u16* __restrict__ X) {
  __shared__ float xyz2s[N2Q * 3];
  __shared__ float n2s[N2Q];
  __shared__ float lrfs[N2Q * 9];
  __shared__ float wps[DPOS * 4];
  __shared__ float pss[DPOS];
  __shared__ float pbs[DPOS];
  __shared__ int idxb[64 * 3];
  __shared__ float rpb[64 * 3 * 4];

  const int t = threadIdx.x;
  const int qb = blockIdx.x * 64;    // 256 blocks
  const int b = qb >> 11;            // uniform per block (64 | 2048)

  for (int i = t; i < N2Q * 3; i += 256) xyz2s[i] = xyz2[b * N2Q * 3 + i];
  for (int i = t; i < N2Q * 9; i += 256) lrfs[i] = lrf2[b * N2Q * 9 + i];
  if (t < DPOS * 4) wps[t] = w_pos[t];
  if (t < DPOS) { pss[t] = pscale[t]; pbs[t] = pbias[t]; }
  __syncthreads();
  if (t < N2Q) {
    float x = xyz2s[t * 3], y = xyz2s[t * 3 + 1], z = xyz2s[t * 3 + 2];
    n2s[t] = x * x + y * y + z * z;
  }
  __syncthreads();

  // ---- phase 1: kNN + rp, one thread per query (t < 64) ----
  if (t < 64) {
    const int q = qb + t;
    const float px = xyz1[q * 3], py = xyz1[q * 3 + 1], pz = xyz1[q * 3 + 2];
    const float pn = px * px + py * py + pz * pz;
    float d0 = 1e30f, d1 = 1e30f, d2v = 1e30f;
    int i0 = 0, i1 = 0, i2 = 0;
    for (int i = 0; i < N2Q; i++) {
      float dt = px * xyz2s[i * 3] + py * xyz2s[i * 3 + 1] + pz * xyz2s[i * 3 + 2];
      float d = pn + n2s[i] - 2.f * dt;
      if (d < d0) {
        d2v = d1; i2 = i1; d1 = d0; i1 = i0; d0 = d; i0 = i;
      } else if (d < d1) {
        d2v = d1; i2 = i1; d1 = d; i1 = i;
      } else if (d < d2v) {
        d2v = d; i2 = i;
      }
    }
    int sel0 = i0, sel1 = i1, sel2 = i2;
    #pragma unroll
    for (int j = 0; j < 3; j++) {
      int id = (j == 0) ? sel0 : (j == 1) ? sel1 : sel2;
      float rx = px - xyz2s[id * 3];
      float ry = py - xyz2s[id * 3 + 1];
      float rz = pz - xyz2s[id * 3 + 2];
      float rn = sqrtf(rx * rx + ry * ry + rz * rz);
      float inv = 1.f / fmaxf(rn, 1e-12f);
      float ux = rx * inv, uy = ry * inv, uz = rz * inv;
      const float* L = lrfs + id * 9;
      float a0 = L[0] * ux + L[1] * uy + L[2] * uz;
      float a1 = L[3] * ux + L[4] * uy + L[5] * uz;
      float a2 = L[6] * ux + L[7] * uy + L[8] * uz;
      idxb[t * 3 + j] = id;
      float* rp = rpb + (t * 3 + j) * 4;
      rp[0] = rn; rp[1] = a0; rp[2] = a1; rp[3] = a2;
    }
  }
  __syncthreads();

  // ---- phase 2: write X rows, 16B chunks, coalesced ----
  // 64 queries * 4 slots * 36 chunks (36*8=288 bf16) = 9216 chunks
  for (int cix = t; cix < 9216; cix += 256) {
    int rl = cix / 36;           // local row 0..255
    int ch = cix - rl * 36;      // chunk 0..35
    int ql = rl >> 2, j = rl & 3;
    u16x8 val;
    if (j == 3) {
      #pragma unroll
      for (int e = 0; e < 8; e++) val[e] = 0;
    } else if (ch < 32) {
      int id = idxb[ql * 3 + j];
      const float* f = feat2 + ((size_t)b * N2Q + id) * C2Q + ch * 8;
      #pragma unroll
      for (int e = 0; e < 8; e++) val[e] = f2bf(f[e]);
    } else {
      const float* rp = rpb + (ql * 3 + j) * 4;
      float r0 = rp[0], r1 = rp[1], r2 = rp[2], r3 = rp[3];
      int ob = (ch - 32) * 8;
      #pragma unroll
      for (int e = 0; e < 8; e++) {
        int o = ob + e;
        float v = wps[o * 4] * r0 + wps[o * 4 + 1] * r1 +
                  wps[o * 4 + 2] * r2 + wps[o * 4 + 3] * r3;
        v = v * pss[o] + pbs[o];
        v = (v >= 0.f) ? v : 0.2f * v;  // LeakyReLU(0.2)
        val[e] = f2bf(v);
      }
    }
    *(u16x8*)(X + ((size_t)(qb * 4) + rl) * KDIM1 + ch * 8) = val;
  }
}

// ---------------------------------------------------------------------------
// GEMM1: H0[m][n] = relu((X[m][:] . W0[n][:]) * s0[n] + b0[n]) as bf16.
// LDS staging both operands with XOR source-column swizzle. Skips j=3 rows.
__global__ void gemm1(const u16* __restrict__ A, const u16* __restrict__ W,
                      const float* __restrict__ s, const float* __restrict__ bz,
                      u16* __restrict__ H) {
  constexpr int K = KDIM1, N = H0Q;
  __shared__ alignas(16) u16 As[128 * 32];
  __shared__ alignas(16) u16 Bs[128 * 32];
  const int id = blockIdx.x;             // 2048 blocks
  const int xcd = id & 7, g = id >> 3;   // g: 0..255
  const int m0 = ((g >> 2) * 8 + xcd) * 128;  // m-tile 0..511
  const int n0 = (g & 3) * 128;               // n-tile 0..3
  const int t = threadIdx.x;
  const int wv = t >> 6, lane = t & 63;
  const int wm = wv >> 1, wn = wv & 1;
  const int quad = lane >> 4, cc = lane & 15;
  const int rlb = wv * 16 + (lane >> 2);   // local staging row (+ i*64)
  const int csw = lane & 3;                // LDS chunk column this lane fills
  const int sA = (cc + (cc >> 2)) & 3;     // read-side swizzle (per lane)
  const int rdoff = ((quad ^ sA) * 8);     // u16 offset of k-chunk in row
  f32x4 acc[4][4] = {};

  for (int k0 = 0; k0 < K; k0 += 32) {
    #pragma unroll
    for (int i = 0; i < 2; i++) {
      int rl = i * 64 + rlb;
      int cg = csw ^ ((rl + (rl >> 2)) & 3);  // global col chunk for this slot
      load16_lds(A + (size_t)(m0 + rl) * K + k0 + cg * 8,
                 (char*)As + i * 4096 + wv * 1024 + (lane << 4));
      load16_lds(W + (size_t)(n0 + rl) * K + k0 + cg * 8,
                 (char*)Bs + i * 4096 + wv * 1024 + (lane << 4));
    }
    __syncthreads();
    bf16x8 af[4], bf[4];
    #pragma unroll
    for (int mt = 0; mt < 4; mt++)
      af[mt] = *(const bf16x8*)(As + (wm * 64 + mt * 16 + cc) * 32 + rdoff);
    #pragma unroll
    for (int nt = 0; nt < 4; nt++)
      bf[nt] = *(const bf16x8*)(Bs + (wn * 64 + nt * 16 + cc) * 32 + rdoff);
    #pragma unroll
    for (int mt = 0; mt < 4; mt++)
      #pragma unroll
      for (int nt = 0; nt < 4; nt++)
        acc[mt][nt] = __builtin_amdgcn_mfma_f32_16x16x32_bf16(
            af[mt], bf[nt], acc[mt][nt], 0, 0, 0);
    __syncthreads();
  }

  #pragma unroll
  for (int nt = 0; nt < 4; nt++) {
    int gn = n0 + wn * 64 + nt * 16 + cc;
    float sv = s[gn], bv = bz[gn];
    #pragma unroll
    for (int mt = 0; mt < 4; mt++) {
      int gm = m0 + wm * 64 + mt * 16 + quad * 4;
      #pragma unroll
      for (int r = 0; r < 3; r++) {  // r==3 is a j=3 pad row: skip store
        float h = acc[mt][nt][r] * sv + bv;
        h = h > 0.f ? h : 0.f;
        H[(size_t)(gm + r) * N + gn] = f2bf(h);
      }
    }
  }
}

// ---------------------------------------------------------------------------
// GEMM2: h1 = relu((H0 . W1^T) * s1 + b1); in-lane sum over j=0..2 (reg 0..2
// of each quad = 3 real neighbor rows of one query); write out[b][n][n1] f32.
// LDS staging both operands with XOR source-column swizzle.
__global__ void gemm2(const u16* __restrict__ A, const u16* __restrict__ W,
                      const float* __restrict__ s, const float* __restrict__ bz,
                      float* __restrict__ out) {
  constexpr int K = H0Q;  // 512
  __shared__ alignas(16) u16 As[128 * 32];
  __shared__ alignas(16) u16 Bs[128 * 32];
  const int id = blockIdx.x;             // 4096 blocks
  const int xcd = id & 7, g = id >> 3;   // g: 0..511
  const int m0 = ((g >> 3) * 8 + xcd) * 128;  // m-tile 0..511
  const int n0 = (g & 7) * 128;               // n-tile 0..7
  const int t = threadIdx.x;
  const int wv = t >> 6, lane = t & 63;
  const int wm = wv >> 1, wn = wv & 1;
  const int quad = lane >> 4, cc = lane & 15;
  const int rlb = wv * 16 + (lane >> 2);
  const int csw = lane & 3;
  const int sA = (cc + (cc >> 2)) & 3;
  const int rdoff = ((quad ^ sA) * 8);
  f32x4 acc[4][4] = {};

  for (int k0 = 0; k0 < K; k0 += 32) {
    #pragma unroll
    for (int i = 0; i < 2; i++) {
      int rl = i * 64 + rlb;
      int cg = csw ^ ((rl + (rl >> 2)) & 3);
      load16_lds(A + (size_t)(m0 + rl) * K + k0 + cg * 8,
                 (char*)As + i * 4096 + wv * 1024 + (lane << 4));
      load16_lds(W + (size_t)(n0 + rl) * K + k0 + cg * 8,
                 (char*)Bs + i * 4096 + wv * 1024 + (lane << 4));
    }
    __syncthreads();
    bf16x8 af[4], bf[4];
    #pragma unroll
    for (int mt = 0; mt < 4; mt++)
      af[mt] = *(const bf16x8*)(As + (wm * 64 + mt * 16 + cc) * 32 + rdoff);
    #pragma unroll
    for (int nt = 0; nt < 4; nt++)
      bf[nt] = *(const bf16x8*)(Bs + (wn * 64 + nt * 16 + cc) * 32 + rdoff);
    #pragma unroll
    for (int mt = 0; mt < 4; mt++)
      #pragma unroll
      for (int nt = 0; nt < 4; nt++)
        acc[mt][nt] = __builtin_amdgcn_mfma_f32_16x16x32_bf16(
            af[mt], bf[nt], acc[mt][nt], 0, 0, 0);
    __syncthreads();
  }

  #pragma unroll
  for (int nt = 0; nt < 4; nt++) {
    int gn = n0 + wn * 64 + nt * 16 + cc;  // output channel 0..1023
    float sv = s[gn], bv = bz[gn];
    #pragma unroll
    for (int mt = 0; mt < 4; mt++) {
      int gm = m0 + wm * 64 + mt * 16 + quad * 4;  // multiple of 4
      int query = gm >> 2;
      int bb = query >> 11, n1 = query & 2047;
      f32x4 v = acc[mt][nt];
      float h0v = v[0] * sv + bv; h0v = h0v > 0.f ? h0v : 0.f;
      float h1v = v[1] * sv + bv; h1v = h1v > 0.f ? h1v : 0.f;
      float h2v = v[2] * sv + bv; h2v = h2v > 0.f ? h2v : 0.f;
      out[((size_t)bb * H1Q + gn) * N1Q + n1] = h0v + h1v + h2v;
    }
  }
}

// ---------------------------------------------------------------------------
extern "C" void kernel_launch(void* const* d_in, const int* in_sizes, int n_in,
                              void* d_out, int out_size, void* d_ws,
                              size_t ws_size, hipStream_t stream) {
  const float* xyz1 = (const float*)d_in[0];
  const float* xyz2 = (const float*)d_in[1];
  const float* feat2 = (const float*)d_in[2];
  const float* lrf2 = (const float*)d_in[3];
  const float* w_pos = (const float*)d_in[4];
  const float* pscale = (const float*)d_in[5];
  const float* pbias = (const float*)d_in[6];
  const float* w0 = (const float*)d_in[7];
  const float* s0 = (const float*)d_in[8];
  const float* b0 = (const float*)d_in[9];
  const float* w1 = (const float*)d_in[10];
  const float* s1 = (const float*)d_in[11];
  const float* b1 = (const float*)d_in[12];
  float* out = (float*)d_out;

  char* ws = (char*)d_ws;
  u16* w0bf = (u16*)(ws + WS_W0BF);
  u16* w1bf = (u16*)(ws + WS_W1BF);
  u16* X = (u16*)(ws + WS_X);
  u16* H0 = (u16*)(ws + WS_H0);

  convert_weights<<<671744 / 256, 256, 0, stream>>>(w0, w1, w0bf, w1bf);
  build_x<<<NQUERY / 64, 256, 0, stream>>>(xyz1, xyz2, feat2, lrf2, w_pos,
                                           pscale, pbias, X);
  gemm1<<<dim3((MROWS / 128) * (H0Q / 128)), 256, 0, stream>>>(X, w0bf, s0,
                                                               b0, H0);
  gemm2<<<dim3((MROWS / 128) * (H1Q / 128)), 256, 0, stream>>>(H0, w1bf, s1,
                                                               b1, out);
}